// Round 2
// baseline (487.324 us; speedup 1.0000x reference)
//
#include <hip/hip_runtime.h>
#include <hip/hip_bf16.h>

// MoE experts, E=8 H=1024 I=4096 T=8192. I/O is FLOAT32 (per reference);
// internal compute bf16 MFMA (threshold 0.109 allows bf16 floor).
// No activation between the two grouped GEMMs -> reassociate:
//   M_e = W1_e @ W2_e   (68.7 GF, weight GEMM, per expert 1024x1024 K=4096)
//   down = x @ M_e      (17.2 GF, token GEMM)
// M^T stored bf16 in d_ws ([E][h2][h1], h1-fast) so the token GEMM's B
// operand is k-contiguous (global_load_lds path).

typedef unsigned short u16;
typedef unsigned int u32;
typedef __attribute__((ext_vector_type(8))) short bf16x8;   // 8 bf16 = 4 VGPR
typedef __attribute__((ext_vector_type(4))) float f32x4;
typedef __attribute__((ext_vector_type(4))) u32 u32x4;

#define E_N 8
#define H_N 1024
#define I_N 4096
#define T_N 8192

// async global->LDS, 16B/lane; LDS dest is wave-uniform base + lane*16
#define GLD2LDS16(g, l)                                                        \
  __builtin_amdgcn_global_load_lds(                                            \
      (const __attribute__((address_space(1))) void*)(g),                      \
      (__attribute__((address_space(3))) void*)(l), 16, 0, 0)

__device__ __forceinline__ u16 f2bf(float f) {
  __hip_bfloat16 h = __float2bfloat16(f);  // RNE
  return *(reinterpret_cast<u16*>(&h));
}

// pack two f32 -> (lo,hi) bf16 pair with round-to-nearest (+0x8000 then take
// high 16 bits via one v_perm_b32). 3 VALU total.
__device__ __forceinline__ u32 pkbf(float lo, float hi) {
  u32 a = __float_as_uint(lo) + 0x8000u;
  u32 b = __float_as_uint(hi) + 0x8000u;
  return __builtin_amdgcn_perm(b, a, 0x07060302u);
}

// ---------------------------------------------------------------------------
// Weight GEMM: per expert e, C[m=h2][n=h1] = sum_i W2[i][h2] * W1[h1][i]
//            = (W1 @ W2)^T, written bf16 to mt[e][h2][h1] (h1-fast).
// A (W2^T tile) transpose-staged from f32; B (W1 rows, k-contiguous f32)
// cvt-staged. Tile 128x128, BK=32, 256 threads (4 waves as 2x2 of 64x64).
// ---------------------------------------------------------------------------
__global__ __launch_bounds__(256) void wgemm_kernel(const float* __restrict__ w1,
                                                    const float* __restrict__ w2,
                                                    u16* __restrict__ mt) {
  // A: chunked layout [c:4][m:128][k:8] u16 (addr = c*1024 + m*8 + (k&7))
  __shared__ u16 ldsA[4096];
  // B: natural layout [n:128][k:32] u16
  __shared__ u16 ldsB[4096];

  const int tid = threadIdx.x;
  const int lane = tid & 63;
  const int wv = tid >> 6;
  const int wm = wv >> 1, wn = wv & 1;
  const int lm = lane & 15, quad = lane >> 4;

  const int e = blockIdx.y;
  const int bm = blockIdx.x >> 3, bn = blockIdx.x & 7;
  const int row0 = bm * 128;  // h2
  const int col0 = bn * 128;  // h1

  const float* w1e = w1 + (size_t)e * H_N * I_N;
  const float* w2e = w2 + (size_t)e * I_N * H_N;
  u16* mte = mt + (size_t)e * H_N * H_N;

  // A transpose staging: wave wv covers k-chunk (8 i-rows), lane covers
  // h2 columns m = 2*lane, 2*lane+1 (float2 load = 2 adjacent h2 at one i).
  const int a_mp = lane * 2;
  const float* gA0 = w2e + (size_t)(8 * wv) * H_N + row0 + a_mp;

  // B staging: row = col0 + seg*64 + (tid>>2), k-offset (tid&3)*8
  const int b_r = tid >> 2;
  const int b_k = (tid & 3) * 8;
  const float* gB0 = w1e + (size_t)(col0 + b_r) * I_N + b_k;
  const float* gB1 = gB0 + (size_t)64 * I_N;
  u16* ldsB_w = ldsB + b_r * 32 + b_k;

  f32x4 acc[4][4];
#pragma unroll
  for (int i = 0; i < 4; i++)
#pragma unroll
    for (int j = 0; j < 4; j++) acc[i][j] = (f32x4){0.f, 0.f, 0.f, 0.f};

  for (int k0 = 0; k0 < I_N; k0 += 32) {
    // ---- A: 8 float2 loads (transpose), pack to bf16, 2x ds_write_b128
    float2 va[8];
    const float* gA = gA0 + (size_t)k0 * H_N;
#pragma unroll
    for (int kk = 0; kk < 8; kk++)
      va[kk] = *(const float2*)(gA + (size_t)kk * H_N);

    // ---- B: 2 segments x (2 float4 loads -> 4 packs -> ds_write_b128)
    float4 f0 = *(const float4*)(gB0 + k0);
    float4 f1 = *(const float4*)(gB0 + k0 + 4);
    float4 f2 = *(const float4*)(gB1 + k0);
    float4 f3 = *(const float4*)(gB1 + k0 + 4);

    u32 evn[4], odd[4];
#pragma unroll
    for (int j = 0; j < 4; j++) {
      evn[j] = pkbf(va[2 * j].x, va[2 * j + 1].x);  // m = 2*lane
      odd[j] = pkbf(va[2 * j].y, va[2 * j + 1].y);  // m = 2*lane+1
    }
    *(u32x4*)(ldsA + wv * 1024 + a_mp * 8) =
        (u32x4){evn[0], evn[1], evn[2], evn[3]};
    *(u32x4*)(ldsA + wv * 1024 + (a_mp + 1) * 8) =
        (u32x4){odd[0], odd[1], odd[2], odd[3]};

    *(u32x4*)ldsB_w = (u32x4){pkbf(f0.x, f0.y), pkbf(f0.z, f0.w),
                              pkbf(f1.x, f1.y), pkbf(f1.z, f1.w)};
    *(u32x4*)(ldsB_w + 64 * 32) = (u32x4){pkbf(f2.x, f2.y), pkbf(f2.z, f2.w),
                                          pkbf(f3.x, f3.y), pkbf(f3.z, f3.w)};

    __syncthreads();

    bf16x8 af[4], bfr[4];
#pragma unroll
    for (int mi = 0; mi < 4; mi++)
      af[mi] = *(const bf16x8*)(ldsA + quad * 1024 + (wm * 64 + mi * 16 + lm) * 8);
#pragma unroll
    for (int ni = 0; ni < 4; ni++)
      bfr[ni] = *(const bf16x8*)(ldsB + (wn * 64 + ni * 16 + lm) * 32 + quad * 8);
#pragma unroll
    for (int mi = 0; mi < 4; mi++)
#pragma unroll
      for (int ni = 0; ni < 4; ni++)
        acc[mi][ni] = __builtin_amdgcn_mfma_f32_16x16x32_bf16(
            af[mi], bfr[ni], acc[mi][ni], 0, 0, 0);

    __syncthreads();
  }

  // C/D layout: col = lane&15, row = quad*4 + reg
  const int orow = row0 + wm * 64 + quad * 4;
  const int ocol = col0 + wn * 64 + lm;
#pragma unroll
  for (int mi = 0; mi < 4; mi++)
#pragma unroll
    for (int ni = 0; ni < 4; ni++)
#pragma unroll
      for (int r = 0; r < 4; r++)
        mte[(size_t)(orow + mi * 16 + r) * H_N + ocol + ni * 16] =
            f2bf(acc[mi][ni][r]);
}

// ---------------------------------------------------------------------------
// Token GEMM: C[t][h2] = sum_h1 x[t][h1] * Mt[e(t)][h2][h1].
// A (x, f32) cvt-staged; B (Mt, bf16 k-contiguous) via global_load_lds.
// Tile 128x128, BK=32, 256 threads. Output stored f32.
// ---------------------------------------------------------------------------
__global__ __launch_bounds__(256) void tgemm_kernel(const float* __restrict__ x,
                                                    const int* __restrict__ bsz,
                                                    const u16* __restrict__ mt,
                                                    float* __restrict__ out) {
  __shared__ u16 ldsA[4096];  // x tile   [m:128][k:32]
  __shared__ u16 ldsB[4096];  // Mt tile  [n:128][k:32]

  const int tid = threadIdx.x;
  const int lane = tid & 63;
  const int wv = tid >> 6;
  const int wm = wv >> 1, wn = wv & 1;
  const int lm = lane & 15, quad = lane >> 4;

  const int bm = blockIdx.x >> 3, bn = blockIdx.x & 7;
  const int row0 = bm * 128;  // token
  const int col0 = bn * 128;  // h2

  // expert lookup (tile assumed within one group; 1024/expert, 128-row tiles)
  int e = 0, start = 0;
#pragma unroll
  for (int i = 0; i < E_N; i++) {
    int b = bsz[i];
    if (row0 >= start + b) { start += b; e = i + 1; }
  }
  const u16* mte = mt + (size_t)e * H_N * H_N;

  const int s_r = tid >> 2;
  const int s_k = (tid & 3) * 8;
  const float* gA0 = x + (size_t)(row0 + s_r) * H_N + s_k;
  const float* gA1 = gA0 + (size_t)64 * H_N;
  const u16* gB0 = mte + (size_t)(col0 + s_r) * H_N + s_k;
  const u16* gB1 = gB0 + (size_t)64 * H_N;
  u16* ldsA_w = ldsA + s_r * 32 + s_k;
  u16* ldsB_dst = ldsB + wv * 512;  // wave-uniform; lane*16B appended by HW

  f32x4 acc[4][4];
#pragma unroll
  for (int i = 0; i < 4; i++)
#pragma unroll
    for (int j = 0; j < 4; j++) acc[i][j] = (f32x4){0.f, 0.f, 0.f, 0.f};

  for (int k0 = 0; k0 < H_N; k0 += 32) {
    GLD2LDS16(gB0 + k0, ldsB_dst);
    GLD2LDS16(gB1 + k0, ldsB_dst + 2048);

    float4 f0 = *(const float4*)(gA0 + k0);
    float4 f1 = *(const float4*)(gA0 + k0 + 4);
    float4 f2 = *(const float4*)(gA1 + k0);
    float4 f3 = *(const float4*)(gA1 + k0 + 4);
    *(u32x4*)ldsA_w = (u32x4){pkbf(f0.x, f0.y), pkbf(f0.z, f0.w),
                              pkbf(f1.x, f1.y), pkbf(f1.z, f1.w)};
    *(u32x4*)(ldsA_w + 64 * 32) = (u32x4){pkbf(f2.x, f2.y), pkbf(f2.z, f2.w),
                                          pkbf(f3.x, f3.y), pkbf(f3.z, f3.w)};

    __syncthreads();

    bf16x8 af[4], bfr[4];
#pragma unroll
    for (int mi = 0; mi < 4; mi++)
      af[mi] = *(const bf16x8*)(ldsA + (wm * 64 + mi * 16 + lm) * 32 + quad * 8);
#pragma unroll
    for (int ni = 0; ni < 4; ni++)
      bfr[ni] = *(const bf16x8*)(ldsB + (wn * 64 + ni * 16 + lm) * 32 + quad * 8);
#pragma unroll
    for (int mi = 0; mi < 4; mi++)
#pragma unroll
      for (int ni = 0; ni < 4; ni++)
        acc[mi][ni] = __builtin_amdgcn_mfma_f32_16x16x32_bf16(
            af[mi], bfr[ni], acc[mi][ni], 0, 0, 0);

    __syncthreads();
  }

  const int orow = row0 + wm * 64 + quad * 4;
  const int ocol = col0 + wn * 64 + lm;
#pragma unroll
  for (int mi = 0; mi < 4; mi++)
#pragma unroll
    for (int ni = 0; ni < 4; ni++)
#pragma unroll
      for (int r = 0; r < 4; r++)
        out[(size_t)(orow + mi * 16 + r) * H_N + ocol + ni * 16] =
            acc[mi][ni][r];
}

extern "C" void kernel_launch(void* const* d_in, const int* in_sizes, int n_in,
                              void* d_out, int out_size, void* d_ws,
                              size_t ws_size, hipStream_t stream) {
  (void)in_sizes; (void)n_in; (void)out_size; (void)ws_size;
  const float* hiddens = (const float*)d_in[0];
  const int* bsz = (const int*)d_in[1];
  const float* w1 = (const float*)d_in[2];
  const float* w2 = (const float*)d_in[3];
  float* out = (float*)d_out;
  u16* mt = (u16*)d_ws;  // [E][1024][1024] bf16 = 16 MiB

  wgemm_kernel<<<dim3(64, E_N), 256, 0, stream>>>(w1, w2, mt);
  tgemm_kernel<<<dim3(512), 256, 0, stream>>>(hiddens, bsz, mt, out);
}

// Round 3
// 483.654 us; speedup vs baseline: 1.0076x; 1.0076x over previous
//
#include <hip/hip_runtime.h>
#include <hip/hip_bf16.h>

// MoE experts, E=8 H=1024 I=4096 T=8192, f32 I/O, bf16 MFMA compute.
// Reassociation (no activation between GEMMs):
//   M_e = W1_e @ W2_e  (68.7 GF)   then   down = x @ M_e  (17.2 GF)
// Round-3 plan: bf16 pre-pass (convert W1, x; transpose-convert W2) so both
// GEMMs are pure m97 structure: k-contiguous bf16 operands, global_load_lds
// width-16 staging, no in-loop VALU packing. bf16 working set (128 MB) fits
// LLC -> re-reads stop missing to HBM (round-2 wgemm fetched 636 MB).

typedef unsigned short u16;
typedef unsigned int u32;
typedef __attribute__((ext_vector_type(8))) short bf16x8;   // 8 bf16 = 4 VGPR
typedef __attribute__((ext_vector_type(4))) float f32x4;
typedef __attribute__((ext_vector_type(4))) u32 u32x4;

#define E_N 8
#define H_N 1024
#define I_N 4096
#define T_N 8192

// async global->LDS, 16B/lane; LDS dest is wave-uniform base + lane*16
#define GLD2LDS16(g, l)                                                        \
  __builtin_amdgcn_global_load_lds(                                            \
      (const __attribute__((address_space(1))) void*)(g),                      \
      (__attribute__((address_space(3))) void*)(l), 16, 0, 0)

// pack two f32 -> (lo,hi) bf16 pair, round-to-nearest (+0x8000, v_perm)
__device__ __forceinline__ u32 pkbf(float lo, float hi) {
  u32 a = __float_as_uint(lo) + 0x8000u;
  u32 b = __float_as_uint(hi) + 0x8000u;
  return __builtin_amdgcn_perm(b, a, 0x07060302u);
}

__device__ __forceinline__ u16 f2bf(float f) {
  __hip_bfloat16 h = __float2bfloat16(f);
  return *(reinterpret_cast<u16*>(&h));
}

// ---------------------------------------------------------------------------
// Elementwise f32 -> bf16, 8 elems/thread (2x float4 in, 1x 16B out)
// ---------------------------------------------------------------------------
__global__ __launch_bounds__(256) void cvt_kernel(const float* __restrict__ src,
                                                  u16* __restrict__ dst) {
  const size_t i = ((size_t)blockIdx.x * 256 + threadIdx.x) * 8;
  float4 a = *(const float4*)(src + i);
  float4 b = *(const float4*)(src + i + 4);
  *(u32x4*)(dst + i) = (u32x4){pkbf(a.x, a.y), pkbf(a.z, a.w),
                               pkbf(b.x, b.y), pkbf(b.z, b.w)};
}

// ---------------------------------------------------------------------------
// W2 [E][I][H] f32  ->  W2T [E][H][I] bf16.  64x64 tiles via LDS (pad 65).
// grid (16 h-tiles, 64 i-tiles, 8 experts), 256 threads.
// ---------------------------------------------------------------------------
__global__ __launch_bounds__(256) void transp_kernel(const float* __restrict__ w2,
                                                     u16* __restrict__ w2t) {
  __shared__ float tile[64 * 65];
  const int tid = threadIdx.x;
  const int h0 = blockIdx.x * 64;
  const int i0 = blockIdx.y * 64;
  const float* src = w2 + (size_t)blockIdx.z * I_N * H_N;
  u16* dst = w2t + (size_t)blockIdx.z * H_N * I_N;

  // load: 4 passes of 16 rows; row-coalesced float4, scalar LDS stores
  {
    const int r = tid >> 4;          // 0..15
    const int c4 = (tid & 15) * 4;   // 0..60
#pragma unroll
    for (int rr = 0; rr < 4; rr++) {
      const int row = rr * 16 + r;
      float4 v = *(const float4*)(src + (size_t)(i0 + row) * H_N + h0 + c4);
      tile[row * 65 + c4 + 0] = v.x;
      tile[row * 65 + c4 + 1] = v.y;
      tile[row * 65 + c4 + 2] = v.z;
      tile[row * 65 + c4 + 3] = v.w;
    }
  }
  __syncthreads();

  // store: h = hh*32 + tid>>3, i-chunk = (tid&7)*8; 2-way-free LDS reads,
  // per-wave 8 rows x 128B contiguous global stores
  {
    const int hr = tid >> 3;        // 0..31
    const int ic = (tid & 7) * 8;   // 0..56
#pragma unroll
    for (int hh = 0; hh < 2; hh++) {
      const int h = hh * 32 + hr;
      u32 p[4];
#pragma unroll
      for (int j = 0; j < 4; j++)
        p[j] = pkbf(tile[(ic + 2 * j) * 65 + h], tile[(ic + 2 * j + 1) * 65 + h]);
      *(u32x4*)(dst + (size_t)(h0 + h) * I_N + i0 + ic) =
          (u32x4){p[0], p[1], p[2], p[3]};
    }
  }
}

// ---------------------------------------------------------------------------
// Weight GEMM (pure m97): Mt[e][h2][h1] = sum_i W2T[e][h2][i] * W1b[e][h1][i]
// A = W2T rows, B = W1b rows, both k-contiguous bf16 via glds.
// Tile 128x128, BK=32, 256 threads (2x2 waves of 64x64).
// ---------------------------------------------------------------------------
__global__ __launch_bounds__(256) void wgemm_kernel(const u16* __restrict__ w2t,
                                                    const u16* __restrict__ w1b,
                                                    u16* __restrict__ mt) {
  __shared__ u16 ldsA[4096];  // [m:128][k:32]
  __shared__ u16 ldsB[4096];  // [n:128][k:32]

  const int tid = threadIdx.x;
  const int lane = tid & 63;
  const int wv = tid >> 6;
  const int wm = wv >> 1, wn = wv & 1;
  const int lm = lane & 15, quad = lane >> 4;

  const int e = blockIdx.x >> 6;
  const int t = blockIdx.x & 63;
  const int row0 = (t >> 3) * 128;  // h2
  const int col0 = (t & 7) * 128;   // h1

  const u16* Ae = w2t + (size_t)e * H_N * I_N;
  const u16* Be = w1b + (size_t)e * H_N * I_N;
  u16* mte = mt + (size_t)e * H_N * H_N;

  const int s_r = tid >> 2;
  const int s_k = (tid & 3) * 8;
  const u16* gA0 = Ae + (size_t)(row0 + s_r) * I_N + s_k;
  const u16* gA1 = gA0 + (size_t)64 * I_N;
  const u16* gB0 = Be + (size_t)(col0 + s_r) * I_N + s_k;
  const u16* gB1 = gB0 + (size_t)64 * I_N;
  u16* ldsA_dst = ldsA + wv * 512;  // wave-uniform; HW appends lane*16B
  u16* ldsB_dst = ldsB + wv * 512;

  f32x4 acc[4][4];
#pragma unroll
  for (int i = 0; i < 4; i++)
#pragma unroll
    for (int j = 0; j < 4; j++) acc[i][j] = (f32x4){0.f, 0.f, 0.f, 0.f};

  for (int k0 = 0; k0 < I_N; k0 += 32) {
    GLD2LDS16(gA0 + k0, ldsA_dst);
    GLD2LDS16(gA1 + k0, ldsA_dst + 2048);
    GLD2LDS16(gB0 + k0, ldsB_dst);
    GLD2LDS16(gB1 + k0, ldsB_dst + 2048);

    __syncthreads();

    bf16x8 af[4], bfr[4];
#pragma unroll
    for (int mi = 0; mi < 4; mi++)
      af[mi] = *(const bf16x8*)(ldsA + (wm * 64 + mi * 16 + lm) * 32 + quad * 8);
#pragma unroll
    for (int ni = 0; ni < 4; ni++)
      bfr[ni] = *(const bf16x8*)(ldsB + (wn * 64 + ni * 16 + lm) * 32 + quad * 8);
#pragma unroll
    for (int mi = 0; mi < 4; mi++)
#pragma unroll
      for (int ni = 0; ni < 4; ni++)
        acc[mi][ni] = __builtin_amdgcn_mfma_f32_16x16x32_bf16(
            af[mi], bfr[ni], acc[mi][ni], 0, 0, 0);

    __syncthreads();
  }

  // C/D: col = lane&15, row = quad*4 + reg
  const int orow = row0 + wm * 64 + quad * 4;
  const int ocol = col0 + wn * 64 + lm;
#pragma unroll
  for (int mi = 0; mi < 4; mi++)
#pragma unroll
    for (int ni = 0; ni < 4; ni++)
#pragma unroll
      for (int r = 0; r < 4; r++)
        mte[(size_t)(orow + mi * 16 + r) * H_N + ocol + ni * 16] =
            f2bf(acc[mi][ni][r]);
}

// ---------------------------------------------------------------------------
// Token GEMM (pure m97): out[t][h2] = sum_h1 xb[t][h1] * Mt[e(t)][h2][h1]
// Tile 128x128, BK=32. Output f32.
// ---------------------------------------------------------------------------
__global__ __launch_bounds__(256) void tgemm_kernel(const u16* __restrict__ xb,
                                                    const int* __restrict__ bsz,
                                                    const u16* __restrict__ mt,
                                                    float* __restrict__ out) {
  __shared__ u16 ldsA[4096];  // x tile  [m:128][k:32]
  __shared__ u16 ldsB[4096];  // Mt tile [n:128][k:32]

  const int tid = threadIdx.x;
  const int lane = tid & 63;
  const int wv = tid >> 6;
  const int wm = wv >> 1, wn = wv & 1;
  const int lm = lane & 15, quad = lane >> 4;

  const int bm = blockIdx.x >> 3, bn = blockIdx.x & 7;
  const int row0 = bm * 128;  // token
  const int col0 = bn * 128;  // h2

  int e = 0, start = 0;
#pragma unroll
  for (int i = 0; i < E_N; i++) {
    int b = bsz[i];
    if (row0 >= start + b) { start += b; e = i + 1; }
  }
  const u16* mte = mt + (size_t)e * H_N * H_N;

  const int s_r = tid >> 2;
  const int s_k = (tid & 3) * 8;
  const u16* gA0 = xb + (size_t)(row0 + s_r) * H_N + s_k;
  const u16* gA1 = gA0 + (size_t)64 * H_N;
  const u16* gB0 = mte + (size_t)(col0 + s_r) * H_N + s_k;
  const u16* gB1 = gB0 + (size_t)64 * H_N;
  u16* ldsA_dst = ldsA + wv * 512;
  u16* ldsB_dst = ldsB + wv * 512;

  f32x4 acc[4][4];
#pragma unroll
  for (int i = 0; i < 4; i++)
#pragma unroll
    for (int j = 0; j < 4; j++) acc[i][j] = (f32x4){0.f, 0.f, 0.f, 0.f};

  for (int k0 = 0; k0 < H_N; k0 += 32) {
    GLD2LDS16(gA0 + k0, ldsA_dst);
    GLD2LDS16(gA1 + k0, ldsA_dst + 2048);
    GLD2LDS16(gB0 + k0, ldsB_dst);
    GLD2LDS16(gB1 + k0, ldsB_dst + 2048);

    __syncthreads();

    bf16x8 af[4], bfr[4];
#pragma unroll
    for (int mi = 0; mi < 4; mi++)
      af[mi] = *(const bf16x8*)(ldsA + (wm * 64 + mi * 16 + lm) * 32 + quad * 8);
#pragma unroll
    for (int ni = 0; ni < 4; ni++)
      bfr[ni] = *(const bf16x8*)(ldsB + (wn * 64 + ni * 16 + lm) * 32 + quad * 8);
#pragma unroll
    for (int mi = 0; mi < 4; mi++)
#pragma unroll
      for (int ni = 0; ni < 4; ni++)
        acc[mi][ni] = __builtin_amdgcn_mfma_f32_16x16x32_bf16(
            af[mi], bfr[ni], acc[mi][ni], 0, 0, 0);

    __syncthreads();
  }

  const int orow = row0 + wm * 64 + quad * 4;
  const int ocol = col0 + wn * 64 + lm;
#pragma unroll
  for (int mi = 0; mi < 4; mi++)
#pragma unroll
    for (int ni = 0; ni < 4; ni++)
#pragma unroll
      for (int r = 0; r < 4; r++)
        out[(size_t)(orow + mi * 16 + r) * H_N + ocol + ni * 16] =
            acc[mi][ni][r];
}

extern "C" void kernel_launch(void* const* d_in, const int* in_sizes, int n_in,
                              void* d_out, int out_size, void* d_ws,
                              size_t ws_size, hipStream_t stream) {
  (void)in_sizes; (void)n_in; (void)out_size; (void)ws_size;
  const float* hiddens = (const float*)d_in[0];
  const int* bsz = (const int*)d_in[1];
  const float* w1 = (const float*)d_in[2];
  const float* w2 = (const float*)d_in[3];
  float* out = (float*)d_out;

  // workspace layout (bytes): w1b 64MB | w2t 64MB | xb 16MB | mt 16MB = 160MB
  char* ws = (char*)d_ws;
  u16* w1b = (u16*)(ws);
  u16* w2t = (u16*)(ws + (size_t)64 * 1024 * 1024);
  u16* xb  = (u16*)(ws + (size_t)128 * 1024 * 1024);
  u16* mt  = (u16*)(ws + (size_t)144 * 1024 * 1024);

  // pre-pass: bf16 conversions (+ W2 transpose)
  cvt_kernel<<<dim3(16384), 256, 0, stream>>>(w1, w1b);          // W1: 33.5M elems
  cvt_kernel<<<dim3(4096), 256, 0, stream>>>(hiddens, xb);       // x: 8.4M elems
  transp_kernel<<<dim3(16, 64, E_N), 256, 0, stream>>>(w2, w2t);

  // M^T per expert (8x8 tiles x 8 experts)
  wgemm_kernel<<<dim3(512), 256, 0, stream>>>(w2t, w1b, mt);
  // down = x @ M
  tgemm_kernel<<<dim3(512), 256, 0, stream>>>(xb, bsz, mt, out);
}